// Round 1
// baseline (33.881 us; speedup 1.0000x reference)
//
#include <hip/hip_runtime.h>
#include <hip/hip_bf16.h>
#include <math.h>

#define IMG_N   256
#define NFACE   512
#define FEPS    1e-8f
#define FSTRIDE 12              // 9 coeffs + 3 pad -> 48 B, float4-aligned
#define T_CLIP  13.815511f      // -log(1e-6); clip region of log1p(-alpha)

// ---------------- Kernel 1: per-face edge-line coefficients ----------------
// For each face, transform its 3 vertices (look_at + perspective, constants
// baked from distance=2.732, el=0, az=90, view=30deg) and emit, per edge,
// (A,B,C) with signed scaled distance d(px,py) = A*px + B*py + C.
__global__ __launch_bounds__(512) void silprep_kernel(
    const float* __restrict__ verts, const int* __restrict__ faces,
    float* __restrict__ fdata, float* __restrict__ out)
{
    int f = threadIdx.x;
    if (f == 0) out[0] = 0.0f;           // zero the loss accumulator
    if (f >= NFACE) return;

    const float D2R  = 0.017453292519943295f;
    const float dist = 2.732f;
    const float elr  = 0.0f;
    const float azr  = 90.0f * D2R;

    float ex = dist * cosf(elr) * sinf(azr);
    float ey = dist * sinf(elr);
    float ez = -dist * cosf(elr) * cosf(azr);

    // z-axis = normalize(-eye)
    float zx = -ex, zy = -ey, zz = -ez;
    float n = sqrtf(zx * zx + zy * zy + zz * zz) + FEPS;
    zx /= n; zy /= n; zz /= n;
    // x-axis = normalize(cross(up=(0,1,0), z)) = normalize((zz, 0, -zx))
    float xx_ = zz, xy_ = 0.0f, xz_ = -zx;
    n = sqrtf(xx_ * xx_ + xy_ * xy_ + xz_ * xz_) + FEPS;
    xx_ /= n; xy_ /= n; xz_ /= n;
    // y-axis = normalize(cross(z, x))
    float yx = zy * xz_ - zz * xy_;
    float yy = zz * xx_ - zx * xz_;
    float yz = zx * xy_ - zy * xx_;
    n = sqrtf(yx * yx + yy * yy + yz * yz) + FEPS;
    yx /= n; yy /= n; yz /= n;

    const float tanv = tanf(30.0f * D2R);

    int i0 = faces[f * 3 + 0];
    int i1 = faces[f * 3 + 1];
    int i2 = faces[f * 3 + 2];

    float p2d[3][2];
    int idx[3] = { i0, i1, i2 };
#pragma unroll
    for (int k = 0; k < 3; ++k) {
        float vx = verts[idx[k] * 3 + 0] - ex;
        float vy = verts[idx[k] * 3 + 1] - ey;
        float vz = verts[idx[k] * 3 + 2] - ez;
        float cx = vx * xx_ + vy * xy_ + vz * xz_;
        float cy = vx * yx  + vy * yy  + vz * yz;
        float cz = vx * zx  + vy * zy  + vz * zz;
        float inv = 1.0f / (cz * tanv + FEPS);
        p2d[k][0] = cx * inv;
        p2d[k][1] = cy * inv;
    }

    float axp = p2d[0][0], ayp = p2d[0][1];
    float bxp = p2d[1][0], byp = p2d[1][1];
    float cxp = p2d[2][0], cyp = p2d[2][1];

    float area = (bxp - axp) * (cyp - ayp) - (byp - ayp) * (cxp - axp);
    float sgn = (area >= 0.0f) ? 1.0f : -1.0f;

    float* o = fdata + f * FSTRIDE;
#define EDGE(P0X, P0Y, P1X, P1Y, SLOT)                                   \
    {                                                                    \
        float ex_ = (P1X) - (P0X);                                       \
        float ey_ = (P1Y) - (P0Y);                                       \
        float il = rsqrtf(ex_ * ex_ + ey_ * ey_ + FEPS) * sgn;           \
        o[(SLOT) * 3 + 0] = -ey_ * il;                                   \
        o[(SLOT) * 3 + 1] =  ex_ * il;                                   \
        o[(SLOT) * 3 + 2] = (ey_ * (P0X) - ex_ * (P0Y)) * il;            \
    }
    EDGE(axp, ayp, bxp, byp, 0)   // a -> b
    EDGE(bxp, byp, cxp, cyp, 1)   // b -> c
    EDGE(cxp, cyp, axp, ayp, 2)   // c -> a
#undef EDGE
    o[9] = 0.0f; o[10] = 0.0f; o[11] = 0.0f;
}

// ---------------- Kernel 2: rasterize + loss ----------------
// 1024 blocks x 256 threads. Block b covers pixels [b*64, b*64+64);
// the 4 waves of the block each sum 128 faces (face-split for occupancy).
__global__ __launch_bounds__(256) void silloss_kernel(
    const float* __restrict__ fdata, const float* __restrict__ ref,
    float* __restrict__ out)
{
    __shared__ float sf[NFACE * FSTRIDE];
    __shared__ float red[64][5];

    int tid = threadIdx.x;

    // stage face table into LDS (coalesced float4)
    const float4* g4 = (const float4*)fdata;
    float4* s4 = (float4*)sf;
#pragma unroll
    for (int i = 0; i < NFACE * FSTRIDE / 4 / 256; ++i)
        s4[tid + i * 256] = g4[tid + i * 256];
    __syncthreads();

    int lane = tid & 63;
    int q = tid >> 6;                 // which face quarter this wave sums
    int pixel = blockIdx.x * 64 + lane;
    int row = pixel >> 8;
    int col = pixel & 255;

    float px = ((float)col + 0.5f) * (2.0f / 256.0f) - 1.0f;
    float py = -(((float)row + 0.5f) * (2.0f / 256.0f) - 1.0f);

    float s = 0.0f;
    int fbeg = q * (NFACE / 4);
#pragma unroll 4
    for (int f = fbeg; f < fbeg + NFACE / 4; ++f) {
        const float* fd = &sf[f * FSTRIDE];
        float4 e01 = *(const float4*)(fd);       // A0 B0 C0 A1
        float4 e12 = *(const float4*)(fd + 4);   // B1 C1 A2 B2
        float  c2  = fd[8];                      // C2
        float d0 = fmaf(e01.x, px, fmaf(e01.y, py, e01.z));
        float d1 = fmaf(e01.w, px, fmaf(e12.x, py, e12.y));
        float d2 = fmaf(e12.z, px, fmaf(e12.w, py, c2));
        float dmin = fminf(d0, fminf(d1, d2));
        float x = dmin * 100.0f;                 // dmin / SIGMA
        float e = __expf(x);                     // inf ok: log->inf->clamped
        float c = fminf(__logf(1.0f + e), T_CLIP);
        s += c;
    }

    red[lane][q] = s;
    __syncthreads();

    if (tid < 64) {
        float stot = red[tid][0] + red[tid][1] + red[tid][2] + red[tid][3];
        float sil = 1.0f - __expf(-stot);
        float d = sil - ref[pixel];
        float v = d * d;
#pragma unroll
        for (int off = 32; off > 0; off >>= 1)
            v += __shfl_down(v, off);
        if (tid == 0) atomicAdd(out, v);
    }
}

extern "C" void kernel_launch(void* const* d_in, const int* in_sizes, int n_in,
                              void* d_out, int out_size, void* d_ws, size_t ws_size,
                              hipStream_t stream) {
    const float* verts = (const float*)d_in[0];   // (1,4096,3) f32
    const int* faces = (const int*)d_in[1];       // (1,512,3) i32
    const float* ref = (const float*)d_in[2];     // (256,256) f32
    float* out = (float*)d_out;                   // scalar loss
    float* fdata = (float*)d_ws;                  // 512*12 floats = 24 KiB

    silprep_kernel<<<1, 512, 0, stream>>>(verts, faces, fdata, out);
    silloss_kernel<<<(IMG_N * IMG_N) / 64, 256, 0, stream>>>(fdata, ref, out);
}

// Round 2
// 28.927 us; speedup vs baseline: 1.1713x; 1.1713x over previous
//
#include <hip/hip_runtime.h>
#include <hip/hip_bf16.h>
#include <math.h>

// Camera constants fold completely: eye=(2.732,0,~0), R = {x=(0,0,1),y=(0,1,0),z=(-1,0,0)}
// => cam = (vz, vy, 2.732-vx); screen X = vz*inv, Y = vy*inv, inv = 1/((2.732-vx)*tan30+EPS)
#define FEPS   1e-8f
#define TANV   0.57735026918962576f   // tan(30 deg)
#define SCL    144.26950408889634f    // (1/SIGMA=100) * log2(e): edge dist -> log2-domain
#define CLIP2  19.931568569324174f    // -log(1e-6)/ln2 : clip of softplus in log2 units
#define EYEX   2.732f
#define PXD    0.0078125f             // 2/256

__device__ __forceinline__ float bperm1(int rotB, float v) {
    return __int_as_float(__builtin_amdgcn_ds_bpermute(rotB, __float_as_int(v)));
}

// One fused kernel. Block = 4 waves = one 64-pixel row segment.
// Wave q owns faces [q*128, q*128+128): lane holds coeffs of 2 faces in regs.
// Inner loop: 64 steps; at step s lane l evaluates its 2 faces at pixel (l+s)&63.
// px and the per-pixel accumulator ride a 1-lane ring rotation (ds_bpermute).
__global__ __launch_bounds__(256) void sil_kernel(
    const float* __restrict__ verts, const int* __restrict__ faces,
    const float* __restrict__ ref, float* __restrict__ out)
{
    __shared__ float red[64][5];
    const int tid  = threadIdx.x;
    const int lane = tid & 63;
    const int q    = tid >> 6;
    const int tile = blockIdx.x;          // 1024 tiles: row = tile>>2, cols [(tile&3)*64 ...)
    const int row  = tile >> 2;
    const int col0 = (tile & 3) << 6;

    const float py = 1.0f - ((float)row + 0.5f) * PXD;

    // ---- per-lane: edge coefficients for this lane's 2 faces (A*px + (B*py+C)) ----
    float A[2][3], E[2][3];
#pragma unroll
    for (int k = 0; k < 2; ++k) {
        const int f  = q * 128 + k * 64 + lane;
        const int i0 = faces[3*f+0], i1 = faces[3*f+1], i2 = faces[3*f+2];
        const int ii[3] = { i0, i1, i2 };
        float X[3], Y[3];
#pragma unroll
        for (int v = 0; v < 3; ++v) {
            const float vx = verts[3*ii[v]+0];
            const float vy = verts[3*ii[v]+1];
            const float vz = verts[3*ii[v]+2];
            const float inv = __builtin_amdgcn_rcpf(fmaf(EYEX - vx, TANV, FEPS));
            X[v] = vz * inv;
            Y[v] = vy * inv;
        }
        const float area = (X[1]-X[0])*(Y[2]-Y[0]) - (Y[1]-Y[0])*(X[2]-X[0]);
        const float sgn  = (area >= 0.0f) ? SCL : -SCL;   // sign * sigma/log2 prescale
#pragma unroll
        for (int e = 0; e < 3; ++e) {
            const int   e1 = (e == 2) ? 0 : e + 1;
            const float ex = X[e1] - X[e], ey = Y[e1] - Y[e];
            const float il = __builtin_amdgcn_rsqf(fmaf(ex,ex,fmaf(ey,ey,FEPS))) * sgn;
            const float Ae = -ey * il;
            const float Be =  ex * il;
            const float Ce = (ey * X[e] - ex * Y[e]) * il;
            A[k][e] = Ae;
            E[k][e] = fmaf(Be, py, Ce);   // row-uniform part hoisted out of the loop
        }
    }

    // ---- ring loop over the 64 pixels of this row segment ----
    const int rotB = ((lane + 1) & 63) << 2;              // bpermute byte index: pull lane+1
    float px  = fmaf((float)(col0 + lane) + 0.5f, PXD, -1.0f);
    float acc = 0.0f;
#pragma unroll 8
    for (int s = 0; s < 64; ++s) {
        const float u0 = fminf(fminf(fmaf(A[0][0],px,E[0][0]), fmaf(A[0][1],px,E[0][1])),
                               fmaf(A[0][2],px,E[0][2]));
        const float u1 = fminf(fminf(fmaf(A[1][0],px,E[1][0]), fmaf(A[1][1],px,E[1][1])),
                               fmaf(A[1][2],px,E[1][2]));
        // softplus in log2 domain; inf-safe (exp2->inf => log2->inf => clamped)
        const float c0 = fminf(__builtin_amdgcn_logf(1.0f + __builtin_amdgcn_exp2f(u0)), CLIP2);
        const float c1 = fminf(__builtin_amdgcn_logf(1.0f + __builtin_amdgcn_exp2f(u1)), CLIP2);
        acc = bperm1(rotB, acc + c0 + c1);                // add to own pixel, then rotate
        px  = bperm1(rotB, px);
    }
    // after 64 rotations lane l again holds pixel l's partial sum

    red[lane][q] = acc;
    __syncthreads();

    if (tid < 64) {
        const float S2  = red[tid][0] + red[tid][1] + red[tid][2] + red[tid][3];
        const float sil = 1.0f - __builtin_amdgcn_exp2f(-S2);   // 1 - exp(-sum_nats)
        const float d   = sil - ref[tile * 64 + tid];
        float v = d * d;
#pragma unroll
        for (int off = 32; off > 0; off >>= 1)
            v += __shfl_down(v, off);
        if (tid == 0) atomicAdd(out, v);
    }
}

extern "C" void kernel_launch(void* const* d_in, const int* in_sizes, int n_in,
                              void* d_out, int out_size, void* d_ws, size_t ws_size,
                              hipStream_t stream) {
    const float* verts = (const float*)d_in[0];   // (1,4096,3) f32
    const int*   faces = (const int*)d_in[1];     // (1,512,3) i32
    const float* ref   = (const float*)d_in[2];   // (256,256) f32
    float*       out   = (float*)d_out;           // scalar loss

    hipMemsetAsync(d_out, 0, sizeof(float), stream);
    sil_kernel<<<1024, 256, 0, stream>>>(verts, faces, ref, out);
}

// Round 3
// 26.554 us; speedup vs baseline: 1.2759x; 1.0893x over previous
//
#include <hip/hip_runtime.h>
#include <hip/hip_bf16.h>
#include <math.h>

// Camera folds to: screen X = vz*inv, Y = vy*inv, inv = 1/((2.732-vx)*tan30+EPS)
#define FEPS   1e-8f
#define TANV   0.57735026918962576f   // tan(30 deg)
#define SCL    144.26950408889634f    // (1/SIGMA=100) * log2(e): coeffs pre-scaled to log2 domain
#define CLIP2  19.931568569324174f    // -log(1e-6)/ln2
#define TFAR   -20.0f                 // exp2(-20): contribution < 1e-6 nats -> skip
#define EYEX   2.732f
#define PXD    0.0078125f             // 2/256
#define NFACE  512

// ---------------- prep: per-face edge coeffs (pre-scaled), 2 blocks x 256 ----------------
// Record per face: 3 x float4 {A,B,C,AH} with u_e(px,py)=A*px+B*py+C (log2-scaled),
// AH = |A|*0.25 = interval half-width over a 64-px row segment.
__global__ __launch_bounds__(256) void prep_kernel(
    const float* __restrict__ verts, const int* __restrict__ faces,
    float* __restrict__ fd, float* __restrict__ out)
{
    int f = blockIdx.x * 256 + threadIdx.x;
    if (f == 0) out[0] = 0.0f;                 // zero loss accumulator
    if (f >= NFACE) return;

    int ii[3] = { faces[3*f], faces[3*f+1], faces[3*f+2] };
    float X[3], Y[3];
#pragma unroll
    for (int v = 0; v < 3; ++v) {
        float vx = verts[3*ii[v]+0];
        float vy = verts[3*ii[v]+1];
        float vz = verts[3*ii[v]+2];
        float inv = __builtin_amdgcn_rcpf(fmaf(EYEX - vx, TANV, FEPS));
        X[v] = vz * inv;
        Y[v] = vy * inv;
    }
    float area = (X[1]-X[0])*(Y[2]-Y[0]) - (Y[1]-Y[0])*(X[2]-X[0]);
    float sgn = (area >= 0.0f) ? SCL : -SCL;

    float4* dst = (float4*)(fd + f * 12);
#pragma unroll
    for (int e = 0; e < 3; ++e) {
        int e1 = (e == 2) ? 0 : e + 1;
        float ex = X[e1] - X[e], ey = Y[e1] - Y[e];
        float il = __builtin_amdgcn_rsqf(fmaf(ex,ex,fmaf(ey,ey,FEPS))) * sgn;
        float A = -ey * il;
        float B =  ex * il;
        float C = (ey * X[e] - ex * Y[e]) * il;
        dst[e] = make_float4(A, B, C, fabsf(A) * 0.25f);
    }
}

// ---------------- main: classify + band-eval + loss ----------------
// 1024 blocks x 256. Block = one 64-px row segment; wave q owns faces [q*128,(q+1)*128).
__global__ __launch_bounds__(256) void main_kernel(
    const float* __restrict__ fd, const float* __restrict__ ref,
    float* __restrict__ out)
{
    __shared__ float sf[NFACE * 12];
    __shared__ float red[64][5];

    const int tid = threadIdx.x, lane = tid & 63, q = tid >> 6;
    const int tile = blockIdx.x, row = tile >> 2, col0 = (tile & 3) << 6;
    const float py  = 1.0f - ((float)row + 0.5f) * PXD;
    const float pxc = (float)(col0 + 32) * PXD - 1.0f;   // segment center

    // stage face table to LDS (for broadcast reads in the band loop)
    const float4* g4 = (const float4*)fd;
    float4* s4 = (float4*)sf;
#pragma unroll
    for (int i = 0; i < 6; ++i) s4[tid + i * 256] = g4[tid + i * 256];

    // classification: lane handles faces q*128+lane and q*128+64+lane (global reads)
    unsigned long long bmask[2];
    int incnt = 0;
#pragma unroll
    for (int k = 0; k < 2; ++k) {
        int f = q * 128 + k * 64 + lane;
        const float4* c = (const float4*)(fd + f * 12);
        float4 ca = c[0], cb = c[1], cc = c[2];
        float u0 = fmaf(ca.x, pxc, fmaf(ca.y, py, ca.z));
        float u1 = fmaf(cb.x, pxc, fmaf(cb.y, py, cb.z));
        float u2 = fmaf(cc.x, pxc, fmaf(cc.y, py, cc.z));
        float lo = fminf(fminf(u0 - ca.w, u1 - cb.w), u2 - cc.w);
        float hi = fminf(fminf(u0 + ca.w, u1 + cb.w), u2 + cc.w);
        bool inside = (lo >= CLIP2);            // softplus>=u>=CLIP2 for every pixel: exact
        bool band = (!inside) && (hi > TFAR);
        bmask[k] = __ballot(band);
        incnt += __popcll(__ballot(inside));
    }
    __syncthreads();

    const float px = fmaf((float)(col0 + lane) + 0.5f, PXD, -1.0f);
    float acc = (float)incnt * CLIP2;

#pragma unroll
    for (int k = 0; k < 2; ++k) {
        unsigned long long m = bmask[k];
        const int base = q * 128 + k * 64;
        if (m) {
            int f = base + (int)__builtin_ctzll(m); m &= m - 1;
            float4 ca = *(const float4*)&sf[f*12];
            float4 cb = *(const float4*)&sf[f*12+4];
            float4 cc = *(const float4*)&sf[f*12+8];
            while (m) {
                int f2 = base + (int)__builtin_ctzll(m); m &= m - 1;
                float4 na = *(const float4*)&sf[f2*12];     // prefetch next face
                float4 nb = *(const float4*)&sf[f2*12+4];
                float4 nc = *(const float4*)&sf[f2*12+8];
                float u = fminf(fminf(fmaf(ca.x, px, fmaf(ca.y, py, ca.z)),
                                      fmaf(cb.x, px, fmaf(cb.y, py, cb.z))),
                                      fmaf(cc.x, px, fmaf(cc.y, py, cc.z)));
                float t = __builtin_amdgcn_exp2f(u);        // inf-safe
                acc += fminf(__builtin_amdgcn_logf(1.0f + t), CLIP2);
                ca = na; cb = nb; cc = nc;
            }
            float u = fminf(fminf(fmaf(ca.x, px, fmaf(ca.y, py, ca.z)),
                                  fmaf(cb.x, px, fmaf(cb.y, py, cb.z))),
                                  fmaf(cc.x, px, fmaf(cc.y, py, cc.z)));
            float t = __builtin_amdgcn_exp2f(u);
            acc += fminf(__builtin_amdgcn_logf(1.0f + t), CLIP2);
        }
    }

    red[lane][q] = acc;
    __syncthreads();

    if (tid < 64) {
        float S   = red[tid][0] + red[tid][1] + red[tid][2] + red[tid][3];
        float sil = 1.0f - __builtin_amdgcn_exp2f(-S);
        float d   = sil - ref[tile * 64 + tid];
        float v = d * d;
#pragma unroll
        for (int off = 32; off > 0; off >>= 1)
            v += __shfl_down(v, off);
        if (tid == 0) atomicAdd(out, v);
    }
}

extern "C" void kernel_launch(void* const* d_in, const int* in_sizes, int n_in,
                              void* d_out, int out_size, void* d_ws, size_t ws_size,
                              hipStream_t stream) {
    const float* verts = (const float*)d_in[0];   // (1,4096,3) f32
    const int*   faces = (const int*)d_in[1];     // (1,512,3) i32
    const float* ref   = (const float*)d_in[2];   // (256,256) f32
    float*       out   = (float*)d_out;           // scalar loss
    float*       fd    = (float*)d_ws;            // 512*12 floats = 24 KiB

    prep_kernel<<<2, 256, 0, stream>>>(verts, faces, fd, out);
    main_kernel<<<1024, 256, 0, stream>>>(fd, ref, out);
}